// Round 5
// baseline (76085.883 us; speedup 1.0000x reference)
//
#include <hip/hip_runtime.h>
#include <cstdint>
#include <cstddef>

// VQ nearest-codebook, two-phase:
//   P1: fp16 MFMA approx scores -> per-row candidate set (superset, margin-sound)
//   P2: exact bitwise-numpy rescore of candidates (R2-verified chain)
constexpr int N_ROWS = 32768;
constexpr int KCODES = 8192;
constexpr int DIMS   = 512;
constexpr int CAND   = 32;
constexpr float MARGIN = 4.5e-4f;   // >= 2B = 4*eps(3.8e-5) + 4*ulp(6.1e-5)

typedef _Float16 half8 __attribute__((ext_vector_type(8)));
typedef float    f32x4 __attribute__((ext_vector_type(4)));

// ---- bitwise replica of np.sum(x*x,-1) fp32 pairwise (AVX512 npyv tree) ----
__global__ __launch_bounds__(256) void rowsq_kernel(const float* __restrict__ x,
                                                    float* __restrict__ out) {
  int row  = (blockIdx.x * 256 + threadIdx.x) >> 6;  // one row per wave
  int lane = threadIdx.x & 63;
  int blk = lane >> 4, l16 = lane & 15;
  const float* p = x + (size_t)row * DIMS + blk * 128 + l16;
  float A[8];
  #pragma unroll
  for (int j = 0; j < 8; ++j) { float v = p[16 * j]; A[j] = __fmul_rn(v, v); }
  float u = __fadd_rn(__fadd_rn(__fadd_rn(A[0], A[1]), __fadd_rn(A[2], A[3])),
                      __fadd_rn(__fadd_rn(A[4], A[5]), __fadd_rn(A[6], A[7])));
  u = __fadd_rn(u, __shfl_xor(u, 8, 64));
  u = __fadd_rn(u, __shfl_xor(u, 4, 64));
  u = __fadd_rn(u, __shfl_xor(u, 2, 64));
  u = __fadd_rn(u, __shfl_xor(u, 1, 64));
  u = __fadd_rn(u, __shfl_xor(u, 16, 64));
  u = __fadd_rn(u, __shfl_xor(u, 32, 64));
  if (lane == 0) out[row] = u;
}

// ---- codebook -> fp16, scaled by 2^11 (exact) to dodge fp16 subnormals ----
__global__ __launch_bounds__(256) void cvt_cb_kernel(const float* __restrict__ cb,
                                                     _Float16* __restrict__ chs) {
  int i = blockIdx.x * 256 + threadIdx.x;          // 4 elements per thread
  float4 v = ((const float4*)cb)[i];
  union { _Float16 h[4]; uint2 u; } p;
  p.h[0] = (_Float16)(v.x * 2048.0f);
  p.h[1] = (_Float16)(v.y * 2048.0f);
  p.h[2] = (_Float16)(v.z * 2048.0f);
  p.h[3] = (_Float16)(v.w * 2048.0f);
  ((uint2*)chs)[i] = p.u;
}

// ---- Phase 1: 128x128 MFMA tiles, running-min + candidate append ----
constexpr int LDH = 72;  // fp16 row stride (64 + 8 pad -> 2-way banks, free)
__global__ __launch_bounds__(256, 2) void vq_mfma_kernel(
    const float* __restrict__ z, const _Float16* __restrict__ chs,
    const float* __restrict__ csq, const float* __restrict__ zsq,
    int* __restrict__ cand_g, int* __restrict__ cnt_g) {
  __shared__ __align__(16) _Float16 Ah[128 * LDH];
  __shared__ __align__(16) _Float16 Bh[128 * LDH];
  __shared__ __align__(16) float rowmin[128];
  __shared__ int cnt[128];
  __shared__ int cand[128 * CAND];

  const int tid  = threadIdx.x;
  const int half = blockIdx.x & 1;
  const int m0   = (blockIdx.x >> 1) * 128;
  const int nt0  = half * (KCODES / 2);
  const int wave = tid >> 6, lane = tid & 63;
  const int wm = wave >> 1, wn = wave & 1;     // 2x2 wave grid of 64x64
  const int q = lane >> 4, r = lane & 15;

  if (tid < 128) { rowmin[tid] = INFINITY; cnt[tid] = 0; }
  __syncthreads();

  // zsq for this lane's 16 accumulator rows: row = wm*64 + mf*16 + q*4 + reg
  float zs[4][4];
  #pragma unroll
  for (int mf = 0; mf < 4; ++mf)
    #pragma unroll
    for (int reg = 0; reg < 4; ++reg)
      zs[mf][reg] = zsq[m0 + wm * 64 + mf * 16 + q * 4 + reg];

  const int rowS = tid >> 1, ksg = (tid & 1) * 32;   // staging map

  for (int t = 0; t < KCODES / 2 / 128; ++t) {
    const int nt = nt0 + t * 128;
    f32x4 acc[4][4];
    #pragma unroll
    for (int mf = 0; mf < 4; ++mf)
      #pragma unroll
      for (int nf = 0; nf < 4; ++nf) acc[mf][nf] = (f32x4){0.f, 0.f, 0.f, 0.f};

    for (int kc = 0; kc < DIMS / 64; ++kc) {
      const int k0 = kc * 64;
      // A: z fp32 -> fp16 on the fly (32 floats/thread)
      {
        const float4* src = (const float4*)(z + (size_t)(m0 + rowS) * DIMS + k0 + ksg);
        _Float16* dst = &Ah[rowS * LDH + ksg];
        #pragma unroll
        for (int i = 0; i < 8; ++i) {
          float4 v = src[i];
          union { _Float16 h[4]; uint2 u; } p;
          p.h[0] = (_Float16)v.x; p.h[1] = (_Float16)v.y;
          p.h[2] = (_Float16)v.z; p.h[3] = (_Float16)v.w;
          *(uint2*)(dst + i * 4) = p.u;
        }
        // B: pre-converted fp16 (32 halfs/thread)
        const uint4* bs = (const uint4*)(chs + (size_t)(nt + rowS) * DIMS + k0 + ksg);
        uint4* bd = (uint4*)&Bh[rowS * LDH + ksg];
        #pragma unroll
        for (int i = 0; i < 4; ++i) bd[i] = bs[i];
      }
      __syncthreads();
      #pragma unroll
      for (int ks = 0; ks < 2; ++ks) {
        half8 af[4], bf[4];
        #pragma unroll
        for (int mf = 0; mf < 4; ++mf)
          af[mf] = *(const half8*)&Ah[(wm * 64 + mf * 16 + r) * LDH + ks * 32 + q * 8];
        #pragma unroll
        for (int nf = 0; nf < 4; ++nf)
          bf[nf] = *(const half8*)&Bh[(wn * 64 + nf * 16 + r) * LDH + ks * 32 + q * 8];
        #pragma unroll
        for (int mf = 0; mf < 4; ++mf)
          #pragma unroll
          for (int nf = 0; nf < 4; ++nf)
            acc[mf][nf] = __builtin_amdgcn_mfma_f32_16x16x32_f16(
                af[mf], bf[nf], acc[mf][nf], 0, 0, 0);
      }
      __syncthreads();
    }

    // epilogue: q' = fl(fl(zsq - acc*2^-10) + csq); C/D: row=q*4+reg, col=r
    float cs[4];
    #pragma unroll
    for (int nf = 0; nf < 4; ++nf) cs[nf] = csq[nt + wn * 64 + nf * 16 + r];
    #pragma unroll
    for (int mf = 0; mf < 4; ++mf) {
      const int rbase = wm * 64 + mf * 16 + q * 4;
      float4 rm4 = *(const float4*)&rowmin[rbase];
      #pragma unroll
      for (int reg = 0; reg < 4; ++reg) {
        float s[4];
        #pragma unroll
        for (int nf = 0; nf < 4; ++nf)
          s[nf] = __fadd_rn(__fmaf_rn(-0.0009765625f, acc[mf][nf][reg],
                                      zs[mf][reg]), cs[nf]);
        float m4 = fminf(fminf(s[0], s[1]), fminf(s[2], s[3]));
        float rm = (reg == 0) ? rm4.x : (reg == 1) ? rm4.y : (reg == 2) ? rm4.z : rm4.w;
        float rmc = fminf(rm, m4);
        if (m4 < rm) rowmin[rbase + reg] = m4;   // benign monotone race
        if (m4 <= rmc + MARGIN) {
          #pragma unroll
          for (int nf = 0; nf < 4; ++nf)
            if (s[nf] <= rmc + MARGIN) {
              int slot = atomicAdd(&cnt[rbase + reg], 1);
              if (slot < CAND)
                cand[(rbase + reg) * CAND + slot] = nt + wn * 64 + nf * 16 + r;
            }
        }
      }
    }
  }
  __syncthreads();
  if (tid < 128) cnt_g[(size_t)half * N_ROWS + m0 + tid] = cnt[tid];
  for (int i = tid; i < 128 * CAND; i += 256)
    cand_g[((size_t)half * N_ROWS + m0 + i / CAND) * CAND + (i % CAND)] = cand[i];
}

// ---- exact bitwise-np score (R2-verified): dual-panel seq FMA chain ----
__device__ __forceinline__ float exact_q(const float* zr, const float* cr,
                                         float zsr, float csr) {
  float s1 = 0.f;
  for (int k = 0; k < 384; k += 8) {
    float4 a0 = *(const float4*)(zr + k), a1 = *(const float4*)(zr + k + 4);
    float4 b0 = *(const float4*)(cr + k), b1 = *(const float4*)(cr + k + 4);
    s1 = __fmaf_rn(a0.x, b0.x, s1); s1 = __fmaf_rn(a0.y, b0.y, s1);
    s1 = __fmaf_rn(a0.z, b0.z, s1); s1 = __fmaf_rn(a0.w, b0.w, s1);
    s1 = __fmaf_rn(a1.x, b1.x, s1); s1 = __fmaf_rn(a1.y, b1.y, s1);
    s1 = __fmaf_rn(a1.z, b1.z, s1); s1 = __fmaf_rn(a1.w, b1.w, s1);
  }
  float s2 = 0.f;
  for (int k = 384; k < 512; k += 8) {
    float4 a0 = *(const float4*)(zr + k), a1 = *(const float4*)(zr + k + 4);
    float4 b0 = *(const float4*)(cr + k), b1 = *(const float4*)(cr + k + 4);
    s2 = __fmaf_rn(a0.x, b0.x, s2); s2 = __fmaf_rn(a0.y, b0.y, s2);
    s2 = __fmaf_rn(a0.z, b0.z, s2); s2 = __fmaf_rn(a0.w, b0.w, s2);
    s2 = __fmaf_rn(a1.x, b1.x, s2); s2 = __fmaf_rn(a1.y, b1.y, s2);
    s2 = __fmaf_rn(a1.z, b1.z, s2); s2 = __fmaf_rn(a1.w, b1.w, s2);
  }
  float cross = __fadd_rn(s1, s2);                 // fl(S1 + S2)
  return __fadd_rn(__fmaf_rn(-2.f, cross, zsr), csr);
}

// ---- Phase 2: rescore candidates exactly, ties -> lowest index, gather ----
__global__ __launch_bounds__(256) void rescore_kernel(
    const float* __restrict__ z, const float* __restrict__ cb,
    const float* __restrict__ zsq, const float* __restrict__ csq,
    const int* __restrict__ cand_g, const int* __restrict__ cnt_g,
    float* __restrict__ zq, float* __restrict__ idx_out) {
  const int wave = threadIdx.x >> 6, lane = threadIdx.x & 63;
  const int row  = blockIdx.x * 4 + wave;
  const float zsr = zsq[row];
  const float* zr = z + (size_t)row * DIMS;
  int c0 = cnt_g[row], c1 = cnt_g[N_ROWS + row];
  float bq = INFINITY; int bc = 0x7fffffff;
  if (c0 <= CAND && c1 <= CAND) {
    int tot = c0 + c1;                              // <= 64
    if (lane < tot) {
      int code = (lane < c0) ? cand_g[(size_t)row * CAND + lane]
                             : cand_g[(size_t)(N_ROWS + row) * CAND + (lane - c0)];
      bq = exact_q(zr, cb + (size_t)code * DIMS, zsr, csq[code]);
      bc = code;
    }
  } else {  // overflow: full exact scan of all codes (rare, correctness net)
    for (int base = 0; base < KCODES; base += 64) {
      int code = base + lane;
      float qv = exact_q(zr, cb + (size_t)code * DIMS, zsr, csq[code]);
      if (qv < bq || (qv == bq && code < bc)) { bq = qv; bc = code; }
    }
  }
  #pragma unroll
  for (int off = 32; off > 0; off >>= 1) {
    float q2 = __shfl_xor(bq, off, 64);
    int   c2 = __shfl_xor(bc, off, 64);
    if (q2 < bq || (q2 == bq && c2 < bc)) { bq = q2; bc = c2; }
  }
  if (lane == 0) idx_out[row] = (float)bc;
  const float4* cbv = (const float4*)(cb + (size_t)bc * DIMS);
  float4* zqv = (float4*)(zq + (size_t)row * DIMS);
  zqv[lane]      = cbv[lane];
  zqv[lane + 64] = cbv[lane + 64];
}

extern "C" void kernel_launch(void* const* d_in, const int* in_sizes, int n_in,
                              void* d_out, int out_size, void* d_ws, size_t ws_size,
                              hipStream_t stream) {
  const float* z  = (const float*)d_in[0];
  const float* cb = (const float*)d_in[1];
  float* out     = (float*)d_out;
  float* zq      = out;
  float* idx_out = out + (size_t)N_ROWS * DIMS;

  // workspace layout (~16.6 MB)
  _Float16* chs = (_Float16*)d_ws;                        // 8192*512 fp16 = 8 MB
  float* zsq = (float*)(chs + (size_t)KCODES * DIMS);     // 32768 f
  float* csq = zsq + N_ROWS;                              // 8192 f
  int* cnt_g = (int*)(csq + KCODES);                      // 2*32768
  int* cand_g = cnt_g + 2 * N_ROWS;                       // 2*32768*32 = 8 MB

  rowsq_kernel<<<N_ROWS / 4, 256, 0, stream>>>(z, zsq);
  rowsq_kernel<<<KCODES / 4, 256, 0, stream>>>(cb, csq);
  cvt_cb_kernel<<<KCODES * DIMS / 1024, 256, 0, stream>>>(cb, chs);
  vq_mfma_kernel<<<(N_ROWS / 128) * 2, 256, 0, stream>>>(z, chs, csq, zsq,
                                                         cand_g, cnt_g);
  rescore_kernel<<<N_ROWS / 4, 256, 0, stream>>>(z, cb, zsq, csq,
                                                 cand_g, cnt_g, zq, idx_out);
}

// Round 6
// 2388.038 us; speedup vs baseline: 31.8612x; 31.8612x over previous
//
#include <hip/hip_runtime.h>
#include <cstdint>
#include <cstddef>

// VQ nearest-codebook, two-phase:
//   P1: fp16 MFMA approx scores -> per-row candidate set (superset, margin-sound)
//       R6 fix: true tile-row-min reduce (shfl + LDS atomicMin) BEFORE append.
//   P2: exact bitwise-numpy rescore of candidates (R2-verified chain)
constexpr int N_ROWS = 32768;
constexpr int KCODES = 8192;
constexpr int DIMS   = 512;
constexpr int CAND   = 32;
constexpr float MARGIN = 1e-3f;   // bound |q'-q_np| ~1.9e-4/side; 2.6x headroom

typedef _Float16 half8 __attribute__((ext_vector_type(8)));
typedef float    f32x4 __attribute__((ext_vector_type(4)));

// ---- bitwise replica of np.sum(x*x,-1) fp32 pairwise (AVX512 npyv tree) ----
__global__ __launch_bounds__(256) void rowsq_kernel(const float* __restrict__ x,
                                                    float* __restrict__ out) {
  int row  = (blockIdx.x * 256 + threadIdx.x) >> 6;  // one row per wave
  int lane = threadIdx.x & 63;
  int blk = lane >> 4, l16 = lane & 15;
  const float* p = x + (size_t)row * DIMS + blk * 128 + l16;
  float A[8];
  #pragma unroll
  for (int j = 0; j < 8; ++j) { float v = p[16 * j]; A[j] = __fmul_rn(v, v); }
  float u = __fadd_rn(__fadd_rn(__fadd_rn(A[0], A[1]), __fadd_rn(A[2], A[3])),
                      __fadd_rn(__fadd_rn(A[4], A[5]), __fadd_rn(A[6], A[7])));
  u = __fadd_rn(u, __shfl_xor(u, 8, 64));
  u = __fadd_rn(u, __shfl_xor(u, 4, 64));
  u = __fadd_rn(u, __shfl_xor(u, 2, 64));
  u = __fadd_rn(u, __shfl_xor(u, 1, 64));
  u = __fadd_rn(u, __shfl_xor(u, 16, 64));
  u = __fadd_rn(u, __shfl_xor(u, 32, 64));
  if (lane == 0) out[row] = u;
}

// ---- fp32 -> fp16 converters (codebook scaled by 2^11, exact pow2) ----
__global__ __launch_bounds__(256) void cvt_cb_kernel(const float* __restrict__ cb,
                                                     _Float16* __restrict__ chs) {
  int i = blockIdx.x * 256 + threadIdx.x;          // 4 elements per thread
  float4 v = ((const float4*)cb)[i];
  union { _Float16 h[4]; uint2 u; } p;
  p.h[0] = (_Float16)(v.x * 2048.0f);
  p.h[1] = (_Float16)(v.y * 2048.0f);
  p.h[2] = (_Float16)(v.z * 2048.0f);
  p.h[3] = (_Float16)(v.w * 2048.0f);
  ((uint2*)chs)[i] = p.u;
}
__global__ __launch_bounds__(256) void cvt_z_kernel(const float* __restrict__ z,
                                                    _Float16* __restrict__ zh) {
  int i = blockIdx.x * 256 + threadIdx.x;
  float4 v = ((const float4*)z)[i];
  union { _Float16 h[4]; uint2 u; } p;
  p.h[0] = (_Float16)v.x; p.h[1] = (_Float16)v.y;
  p.h[2] = (_Float16)v.z; p.h[3] = (_Float16)v.w;
  ((uint2*)zh)[i] = p.u;
}

// ---- Phase 1: 128x128 MFMA tiles, tile-min reduce + candidate append ----
constexpr int LDH = 72;  // fp16 row stride (64 + 8 pad -> 2-way banks, free)
template <bool ZH>
__global__ __launch_bounds__(256, 2) void vq_mfma_kernel(
    const float* __restrict__ z, const _Float16* __restrict__ zh,
    const _Float16* __restrict__ chs,
    const float* __restrict__ csq, const float* __restrict__ zsq,
    int* __restrict__ cand_g, int* __restrict__ cnt_g) {
  __shared__ __align__(16) _Float16 Ah[128 * LDH];
  __shared__ __align__(16) _Float16 Bh[128 * LDH];
  __shared__ unsigned rowmin_u[128];   // positive floats: uint order == float
  __shared__ int cnt[128];
  __shared__ int cand[128 * CAND];

  const int tid  = threadIdx.x;
  const int half = blockIdx.x & 1;
  const int m0   = (blockIdx.x >> 1) * 128;
  const int nt0  = half * (KCODES / 2);
  const int wave = tid >> 6, lane = tid & 63;
  const int wm = wave >> 1, wn = wave & 1;     // 2x2 wave grid of 64x64
  const int q = lane >> 4, r = lane & 15;

  if (tid < 128) { rowmin_u[tid] = 0x7f800000u; cnt[tid] = 0; }
  __syncthreads();

  float zs[4][4];
  #pragma unroll
  for (int mf = 0; mf < 4; ++mf)
    #pragma unroll
    for (int reg = 0; reg < 4; ++reg)
      zs[mf][reg] = zsq[m0 + wm * 64 + mf * 16 + q * 4 + reg];

  const int rowS = tid >> 1, ksg = (tid & 1) * 32;   // staging map

  for (int t = 0; t < KCODES / 2 / 128; ++t) {
    const int nt = nt0 + t * 128;
    f32x4 acc[4][4];
    #pragma unroll
    for (int mf = 0; mf < 4; ++mf)
      #pragma unroll
      for (int nf = 0; nf < 4; ++nf) acc[mf][nf] = (f32x4){0.f, 0.f, 0.f, 0.f};

    for (int kc = 0; kc < DIMS / 64; ++kc) {
      const int k0 = kc * 64;
      if (ZH) {  // pre-converted fp16 z: straight 64B copy
        const uint4* as = (const uint4*)(zh + (size_t)(m0 + rowS) * DIMS + k0 + ksg);
        uint4* ad = (uint4*)&Ah[rowS * LDH + ksg];
        #pragma unroll
        for (int i = 0; i < 4; ++i) ad[i] = as[i];
      } else {   // convert on the fly
        const float4* src = (const float4*)(z + (size_t)(m0 + rowS) * DIMS + k0 + ksg);
        _Float16* dst = &Ah[rowS * LDH + ksg];
        #pragma unroll
        for (int i = 0; i < 8; ++i) {
          float4 v = src[i];
          union { _Float16 h[4]; uint2 u; } p;
          p.h[0] = (_Float16)v.x; p.h[1] = (_Float16)v.y;
          p.h[2] = (_Float16)v.z; p.h[3] = (_Float16)v.w;
          *(uint2*)(dst + i * 4) = p.u;
        }
      }
      {
        const uint4* bs = (const uint4*)(chs + (size_t)(nt + rowS) * DIMS + k0 + ksg);
        uint4* bd = (uint4*)&Bh[rowS * LDH + ksg];
        #pragma unroll
        for (int i = 0; i < 4; ++i) bd[i] = bs[i];
      }
      __syncthreads();
      #pragma unroll
      for (int ks = 0; ks < 2; ++ks) {
        half8 af[4], bf[4];
        #pragma unroll
        for (int mf = 0; mf < 4; ++mf)
          af[mf] = *(const half8*)&Ah[(wm * 64 + mf * 16 + r) * LDH + ks * 32 + q * 8];
        #pragma unroll
        for (int nf = 0; nf < 4; ++nf)
          bf[nf] = *(const half8*)&Bh[(wn * 64 + nf * 16 + r) * LDH + ks * 32 + q * 8];
        #pragma unroll
        for (int mf = 0; mf < 4; ++mf)
          #pragma unroll
          for (int nf = 0; nf < 4; ++nf)
            acc[mf][nf] = __builtin_amdgcn_mfma_f32_16x16x32_f16(
                af[mf], bf[nf], acc[mf][nf], 0, 0, 0);
      }
      __syncthreads();
    }

    // ---- epilogue: q' = fl(fl(zsq - acc*2^-10) + csq); C/D row=q*4+reg col=r
    float cs[4];
    #pragma unroll
    for (int nf = 0; nf < 4; ++nf) cs[nf] = csq[nt + wn * 64 + nf * 16 + r];
    float sv[4][4][4];   // [mf][nf][reg]
    float m4[4][4];      // [mf][reg] lane-local min over nf
    #pragma unroll
    for (int mf = 0; mf < 4; ++mf)
      #pragma unroll
      for (int reg = 0; reg < 4; ++reg) {
        float mn = INFINITY;
        #pragma unroll
        for (int nf = 0; nf < 4; ++nf) {
          float s = __fadd_rn(__fmaf_rn(-0.0009765625f, acc[mf][nf][reg],
                                        zs[mf][reg]), cs[nf]);
          sv[mf][nf][reg] = s;
          mn = fminf(mn, s);
        }
        m4[mf][reg] = mn;
      }
    // wave-level row-min across the 16 lanes (r) sharing each row
    #pragma unroll
    for (int mf = 0; mf < 4; ++mf)
      #pragma unroll
      for (int reg = 0; reg < 4; ++reg) {
        float v = m4[mf][reg];
        v = fminf(v, __shfl_xor(v, 1, 64));
        v = fminf(v, __shfl_xor(v, 2, 64));
        v = fminf(v, __shfl_xor(v, 4, 64));
        v = fminf(v, __shfl_xor(v, 8, 64));
        m4[mf][reg] = v;
      }
    if (r == 0) {
      #pragma unroll
      for (int mf = 0; mf < 4; ++mf)
        #pragma unroll
        for (int reg = 0; reg < 4; ++reg)
          atomicMin(&rowmin_u[wm * 64 + mf * 16 + q * 4 + reg],
                    __float_as_uint(m4[mf][reg]));
    }
    __syncthreads();   // tile-min now includes this tile, for ALL rows
    #pragma unroll
    for (int mf = 0; mf < 4; ++mf)
      #pragma unroll
      for (int reg = 0; reg < 4; ++reg) {
        const int row = wm * 64 + mf * 16 + q * 4 + reg;
        float thr = __uint_as_float(rowmin_u[row]) + MARGIN;
        #pragma unroll
        for (int nf = 0; nf < 4; ++nf)
          if (sv[mf][nf][reg] <= thr) {
            int slot = atomicAdd(&cnt[row], 1);
            if (slot < CAND)
              cand[row * CAND + slot] = nt + wn * 64 + nf * 16 + r;
          }
      }
    // next tile's atomicMin is separated from this append by the kc-loop
    // barriers, so no extra __syncthreads needed here.
  }
  __syncthreads();
  if (tid < 128) cnt_g[(size_t)half * N_ROWS + m0 + tid] = cnt[tid];
  for (int i = tid; i < 128 * CAND; i += 256)
    cand_g[((size_t)half * N_ROWS + m0 + i / CAND) * CAND + (i % CAND)] = cand[i];
}

// ---- exact bitwise-np score (R2-verified): dual-panel seq FMA chain ----
__device__ __forceinline__ float exact_q(const float* zr, const float* cr,
                                         float zsr, float csr) {
  float s1 = 0.f;
  for (int k = 0; k < 384; k += 8) {
    float4 a0 = *(const float4*)(zr + k), a1 = *(const float4*)(zr + k + 4);
    float4 b0 = *(const float4*)(cr + k), b1 = *(const float4*)(cr + k + 4);
    s1 = __fmaf_rn(a0.x, b0.x, s1); s1 = __fmaf_rn(a0.y, b0.y, s1);
    s1 = __fmaf_rn(a0.z, b0.z, s1); s1 = __fmaf_rn(a0.w, b0.w, s1);
    s1 = __fmaf_rn(a1.x, b1.x, s1); s1 = __fmaf_rn(a1.y, b1.y, s1);
    s1 = __fmaf_rn(a1.z, b1.z, s1); s1 = __fmaf_rn(a1.w, b1.w, s1);
  }
  float s2 = 0.f;
  for (int k = 384; k < 512; k += 8) {
    float4 a0 = *(const float4*)(zr + k), a1 = *(const float4*)(zr + k + 4);
    float4 b0 = *(const float4*)(cr + k), b1 = *(const float4*)(cr + k + 4);
    s2 = __fmaf_rn(a0.x, b0.x, s2); s2 = __fmaf_rn(a0.y, b0.y, s2);
    s2 = __fmaf_rn(a0.z, b0.z, s2); s2 = __fmaf_rn(a0.w, b0.w, s2);
    s2 = __fmaf_rn(a1.x, b1.x, s2); s2 = __fmaf_rn(a1.y, b1.y, s2);
    s2 = __fmaf_rn(a1.z, b1.z, s2); s2 = __fmaf_rn(a1.w, b1.w, s2);
  }
  float cross = __fadd_rn(s1, s2);                 // fl(S1 + S2)
  return __fadd_rn(__fmaf_rn(-2.f, cross, zsr), csr);
}

// ---- Phase 2: rescore candidates exactly, ties -> lowest index, gather ----
__global__ __launch_bounds__(256) void rescore_kernel(
    const float* __restrict__ z, const float* __restrict__ cb,
    const float* __restrict__ zsq, const float* __restrict__ csq,
    const int* __restrict__ cand_g, const int* __restrict__ cnt_g,
    float* __restrict__ zq, float* __restrict__ idx_out) {
  const int wave = threadIdx.x >> 6, lane = threadIdx.x & 63;
  const int row  = blockIdx.x * 4 + wave;
  const float zsr = zsq[row];
  const float* zr = z + (size_t)row * DIMS;
  int c0 = cnt_g[row], c1 = cnt_g[N_ROWS + row];
  float bq = INFINITY; int bc = 0x7fffffff;
  if (c0 <= CAND && c1 <= CAND) {
    int tot = c0 + c1;                              // <= 64
    if (lane < tot) {
      int code = (lane < c0) ? cand_g[(size_t)row * CAND + lane]
                             : cand_g[(size_t)(N_ROWS + row) * CAND + (lane - c0)];
      bq = exact_q(zr, cb + (size_t)code * DIMS, zsr, csq[code]);
      bc = code;
    }
  } else {  // overflow: full exact scan (correctness net; ~never taken now)
    for (int base = 0; base < KCODES; base += 64) {
      int code = base + lane;
      float qv = exact_q(zr, cb + (size_t)code * DIMS, zsr, csq[code]);
      if (qv < bq || (qv == bq && code < bc)) { bq = qv; bc = code; }
    }
  }
  #pragma unroll
  for (int off = 32; off > 0; off >>= 1) {
    float q2 = __shfl_xor(bq, off, 64);
    int   c2 = __shfl_xor(bc, off, 64);
    if (q2 < bq || (q2 == bq && c2 < bc)) { bq = q2; bc = c2; }
  }
  if (lane == 0) idx_out[row] = (float)bc;
  const float4* cbv = (const float4*)(cb + (size_t)bc * DIMS);
  float4* zqv = (float4*)(zq + (size_t)row * DIMS);
  zqv[lane]      = cbv[lane];
  zqv[lane + 64] = cbv[lane + 64];
}

extern "C" void kernel_launch(void* const* d_in, const int* in_sizes, int n_in,
                              void* d_out, int out_size, void* d_ws, size_t ws_size,
                              hipStream_t stream) {
  const float* z  = (const float*)d_in[0];
  const float* cb = (const float*)d_in[1];
  float* out     = (float*)d_out;
  float* zq      = out;
  float* idx_out = out + (size_t)N_ROWS * DIMS;

  // workspace layout
  char* w = (char*)d_ws;
  _Float16* cbh = (_Float16*)w;            w += (size_t)KCODES * DIMS * 2;  // 8 MB
  float* zsq = (float*)w;                  w += (size_t)N_ROWS * 4;
  float* csq = (float*)w;                  w += (size_t)KCODES * 4;
  int* cnt_g = (int*)w;                    w += (size_t)2 * N_ROWS * 4;
  int* cand_g = (int*)w;                   w += (size_t)2 * N_ROWS * CAND * 4; // 8MB
  _Float16* zh = (_Float16*)w;             w += (size_t)N_ROWS * DIMS * 2;   // 32 MB
  bool use_zh = ((size_t)(w - (char*)d_ws) <= ws_size);

  rowsq_kernel<<<N_ROWS / 4, 256, 0, stream>>>(z, zsq);
  rowsq_kernel<<<KCODES / 4, 256, 0, stream>>>(cb, csq);
  cvt_cb_kernel<<<KCODES * DIMS / 1024, 256, 0, stream>>>(cb, cbh);
  if (use_zh) {
    cvt_z_kernel<<<N_ROWS * DIMS / 1024, 256, 0, stream>>>(z, zh);
    vq_mfma_kernel<true><<<(N_ROWS / 128) * 2, 256, 0, stream>>>(
        z, zh, cbh, csq, zsq, cand_g, cnt_g);
  } else {
    vq_mfma_kernel<false><<<(N_ROWS / 128) * 2, 256, 0, stream>>>(
        z, nullptr, cbh, csq, zsq, cand_g, cnt_g);
  }
  rescore_kernel<<<N_ROWS / 4, 256, 0, stream>>>(z, cb, zsq, csq,
                                                 cand_g, cnt_g, zq, idx_out);
}